// Round 13
// baseline (424.486 us; speedup 1.0000x reference)
//
#include <hip/hip_runtime.h>

typedef __attribute__((ext_vector_type(8))) short s16x8;
typedef __attribute__((ext_vector_type(4))) float f32x4;

// ---------------- bf16 helpers (RNE) ----------------
__device__ __forceinline__ unsigned short f2bf(float x) {
  unsigned u = __float_as_uint(x);
  u = (u + 0x7fffu + ((u >> 16) & 1u)) >> 16;
  return (unsigned short)u;
}
// v_cvt_pk_bf16_f32: dst.lo = bf16(a), dst.hi = bf16(b), RNE (same as f2bf)
__device__ __forceinline__ unsigned cvt_pk_bf16(float a, float b) {
  unsigned r;
  asm("v_cvt_pk_bf16_f32 %0, %1, %2" : "=v"(r) : "v"(a), "v"(b));
  return r;
}
__device__ __forceinline__ float bflo(unsigned v) { return __uint_as_float(v << 16); }
__device__ __forceinline__ float bfhi(unsigned v) { return __uint_as_float(v & 0xffff0000u); }

// lgkm-only barrier: orders LDS reads/writes across the block WITHOUT draining
// vmcnt -- in-flight global B prefetches survive across it (unlike __syncthreads,
// which hipcc compiles with a full vmcnt(0) drain).
__device__ __forceinline__ void lgkm_barrier() {
  asm volatile("s_waitcnt lgkmcnt(0)" ::: "memory");
  __builtin_amdgcn_s_barrier();
  asm volatile("" ::: "memory");
}

// ---------------- ws layout (ushort units) ----------------
#define FEAT_OFF 0
#define W0F_OFF  2097152
#define W1F_OFF  (W0F_OFF + 24576)
#define W2F_OFF  (W1F_OFF + 65536)
#define W3P_OFF  (W2F_OFF + 65536)
#define WS_TOTAL (W3P_OFF + 512)

// H is stored column-permuted: position k' holds logical col
//   col_log(k') = (k'&0xC0) | ((k'&3)<<4) | ((k'>>2)&15)
__device__ __forceinline__ int col_log(int kp) {
  return (kp & 0xC0) | ((kp & 3) << 4) | ((kp >> 2) & 15);
}

// prep grid map: [0,512) feat transpose tiles; [512,528) W1/W2 coalesced
// reformat chunks (8 per matrix); [528,624) W0 (original path, 24576 el);
// 624 W3p. The old W1/W2 path read W[col_log(kp)*256+n] fully scattered
// (64 lines/wave, ~8MB effective for 512KB of weights); the chunked path
// reads coalesced and stages through LDS.
__global__ void liif_prep(const float* __restrict__ inp,
                          const float* __restrict__ W0,
                          const float* __restrict__ W1,
                          const float* __restrict__ W2,
                          const float* __restrict__ W3,
                          unsigned short* __restrict__ ws) {
  const int bid = blockIdx.x;
  const int tid = threadIdx.x;

  if (bid < 512) {
    // ---- feat transpose: 64(pos) x 64(chan) tile, coalesced both sides ----
    __shared__ unsigned short tile[64 * 66];
    const int posb = bid * 64;
    const int p4 = (tid & 15) * 4;
#pragma unroll
    for (int i = 0; i < 4; ++i) {
      int c = (tid >> 4) + 16 * i;
      const float4 v = *(const float4*)(inp + c * 32768 + posb + p4);
      unsigned short* t = &tile[c * 66 + p4];
      t[0] = f2bf(v.x); t[1] = f2bf(v.y); t[2] = f2bf(v.z); t[3] = f2bf(v.w);
    }
    __syncthreads();
    const int pl = tid >> 2, c0 = (tid & 3) * 16;
    unsigned pw[8];
#pragma unroll
    for (int m = 0; m < 8; ++m) {
      unsigned lo = tile[(c0 + 2 * m) * 66 + pl];
      unsigned hi = tile[(c0 + 2 * m + 1) * 66 + pl];
      pw[m] = lo | (hi << 16);
    }
    uint4* dst = (uint4*)(ws + posb * 64 + tid * 16);
    dst[0] = make_uint4(pw[0], pw[1], pw[2], pw[3]);
    dst[1] = make_uint4(pw[4], pw[5], pw[6], pw[7]);
    return;
  }

  if (bid < 528) {
    // ---- W1/W2 chunk reformat: dest chunk c covers kp in [c*32, c*32+32).
    // Source rows k_src(c,t) = (c&6)*32 + (c&1)*8 + (t&3)*16 + (t>>2)
    // (= col_log(c*32+t), verified). Read coalesced, stage LDS, write linear.
    __shared__ unsigned short lw[32 * 264];
    const int wchunk = bid - 512;
    const int mat = wchunk >> 3, c = wchunk & 7;
    const float* __restrict__ Wsrc = mat ? W2 : W1;
    unsigned short* __restrict__ dst0 = ws + (mat ? W2F_OFF : W1F_OFF) + c * 8192;

    // phase 1: row t = tid>>3 (8 threads/row), cols (tid&7)*4 + i*32 (coalesced)
    const int t = tid >> 3;
    const int ksrc = (c & 6) * 32 + (c & 1) * 8 + (t & 3) * 16 + (t >> 2);
    const int cb = (tid & 7) * 4;
#pragma unroll
    for (int i = 0; i < 8; ++i) {
      int col = cb + i * 32;
      const float4 v = *(const float4*)(Wsrc + ksrc * 256 + col);
      uint2 pk = make_uint2(cvt_pk_bf16(v.x, v.y), cvt_pk_bf16(v.z, v.w));
      *(uint2*)(lw + t * 264 + col) = pk;
    }
    __syncthreads();

    // phase 2: thread writes 32 consecutive shorts at dst0 + tid*32.
    // o = tid*32 + u, u = dl*8 + j: t = tb + j (tb = ((tid>>2)&3)*8),
    // n = n0 + dl (n0 = (tid>>4)*16 + (tid&3)*4).
    const int tb = ((tid >> 2) & 3) * 8;
    const int n0 = (tid >> 4) * 16 + (tid & 3) * 4;
    unsigned pw[16];
#pragma unroll
    for (int dl = 0; dl < 4; ++dl) {
#pragma unroll
      for (int jp = 0; jp < 4; ++jp) {
        unsigned lo = lw[(tb + 2 * jp) * 264 + n0 + dl];
        unsigned hi = lw[(tb + 2 * jp + 1) * 264 + n0 + dl];
        pw[dl * 4 + jp] = lo | (hi << 16);
      }
    }
    uint4* d = (uint4*)(dst0 + tid * 32);
#pragma unroll
    for (int k = 0; k < 4; ++k)
      d[k] = make_uint4(pw[4 * k], pw[4 * k + 1], pw[4 * k + 2], pw[4 * k + 3]);
    return;
  }

  if (bid < 624) {
    // ---- W0 reformat (original path; small, zero-padded K) ----
    int e = (bid - 528) * 256 + tid;
    int j = e & 7, L = (e >> 3) & 63, nt = (e >> 9) & 15, cc = e >> 13;
    int k = cc * 32 + (L >> 4) * 8 + j, n = nt * 16 + (L & 15);
    ws[W0F_OFF + e] = (k < 71) ? f2bf(W0[k * 256 + n]) : (unsigned short)0;
    return;
  }

  // ---- W3p (permuted f32 copy) ----
  {
    float* w3p = (float*)(ws + W3P_OFF);
    w3p[tid] = W3[col_log(tid)];
  }
}

// One GEMM layer: rows 0..63 (A in LDS, bf16), cols 0..255 (B frags in global),
// out = relu(acc) -> H (LDS, stride 264, COLUMN-PERMUTED layout).
// BIAS IS FOLDED INTO THE ACCUMULATOR INIT: C-fragment layout puts all 4 acc
// regs of a thread in ONE column, so acc starts at {bv,bv,bv,bv}.
// nb[] holds THIS layer's c=0 B-frags on entry; if PRE, exits with the NEXT
// layer's c=0 frags in flight (lgkm-only barriers keep vmcnt live across).
template<int KC, bool PRE>
__device__ __forceinline__ void run_layer(const unsigned short* __restrict__ Wf,
                                          const float* __restrict__ bias,
                                          const unsigned short* A, int astride,
                                          unsigned short* H,
                                          const unsigned short* __restrict__ Wnext,
                                          s16x8 (&nb)[4],
                                          int wave, int quad, int l16, int lane) {
  f32x4 acc[4][4];
#pragma unroll
  for (int ntl = 0; ntl < 4; ++ntl) {
    float bv = bias[(wave * 4 + ntl) * 16 + l16];
    f32x4 ai = (f32x4){bv, bv, bv, bv};
#pragma unroll
    for (int rt = 0; rt < 4; ++rt) acc[rt][ntl] = ai;
  }

  __builtin_amdgcn_s_setprio(1);
#pragma unroll
  for (int c = 0; c < KC; ++c) {
    s16x8 a[4];
#pragma unroll
    for (int rt = 0; rt < 4; ++rt)
      a[rt] = *(const s16x8*)(A + (rt * 16 + l16) * astride + c * 32 + quad * 8);
#pragma unroll
    for (int ntl = 0; ntl < 4; ++ntl) {
      int nt = wave * 4 + ntl;
      s16x8 b = (c == 0) ? nb[ntl]
                         : *(const s16x8*)(Wf + (((c * 16 + nt) * 64 + lane) << 3));
#pragma unroll
      for (int rt = 0; rt < 4; ++rt)
        acc[rt][ntl] = __builtin_amdgcn_mfma_f32_16x16x32_bf16(a[rt], b, acc[rt][ntl], 0, 0, 0);
    }
  }
  __builtin_amdgcn_s_setprio(0);

  // issue NEXT layer's c=0 B loads now: latency hides under epilogue + barriers
  if constexpr (PRE) {
#pragma unroll
    for (int ntl = 0; ntl < 4; ++ntl)
      nb[ntl] = *(const s16x8*)(Wnext + (((wave * 4 + ntl) * 64 + lane) << 3));
  }

  lgkm_barrier();  // all waves done reading A (may alias H); vmcnt stays live

  const int cbase = wave * 64 + l16 * 4;  // col' base: 4 ntl-values contiguous
#pragma unroll
  for (int rt = 0; rt < 4; ++rt) {
#pragma unroll
    for (int i = 0; i < 4; ++i) {
      float v0 = fmaxf(acc[rt][0][i], 0.0f);
      float v1 = fmaxf(acc[rt][1][i], 0.0f);
      float v2 = fmaxf(acc[rt][2][i], 0.0f);
      float v3 = fmaxf(acc[rt][3][i], 0.0f);
      int r = rt * 16 + quad * 4 + i;
      uint2 pw = make_uint2(cvt_pk_bf16(v0, v1), cvt_pk_bf16(v2, v3));
      *(uint2*)(H + r * 264 + cbase) = pw;
    }
  }
  lgkm_barrier();  // H visible to all waves; prefetched vmcnt still live
}

__global__ __launch_bounds__(256, 4)
void liif_main(const float* __restrict__ coord,
               const float* __restrict__ cell,
               const float* __restrict__ b0,
               const float* __restrict__ b1,
               const float* __restrict__ b2,
               const float* __restrict__ b3,
               const unsigned short* __restrict__ ws,
               float* __restrict__ out) {
  // LDS: h[64][264] bf16 (stride 264). x[64][104] ALIASES the front of h:
  // run_layer's read->barrier->write discipline makes layer0's in-place-style
  // overwrite of the x region safe. 34.3 KB total -> 4 blocks/CU.
  __shared__ __align__(16) unsigned short sm_h[64 * 264];
  __shared__ float sm_area[64];
  __shared__ float sm_pred[64];
  unsigned short* sm_x = sm_h;  // stride 104 during sampling/layer0

  const unsigned short* feat = ws + FEAT_OFF;
  const int tid = threadIdx.x;
  const int lane = tid & 63;
  const int wave = tid >> 6;
  const int quad = lane >> 4;
  const int l16 = lane & 15;

  // layer0 c=0 B prefetch: in flight across the whole sampling phase
  s16x8 nb[4];
#pragma unroll
  for (int ntl = 0; ntl < 4; ++ntl)
    nb[ntl] = *(const s16x8*)(ws + W0F_OFF + (((wave * 4 + ntl) * 64 + lane) << 3));

  // ---------------- sampling: 4 threads per row, 16 channels each ----------------
  {
    const int row = tid >> 2, p = tid & 3;
    const int ql = row >> 3, s = row & 7;
    const int q = blockIdx.x * 8 + ql;
    const float c0r = coord[q * 3 + 0], c1r = coord[q * 3 + 1], c2r = coord[q * 3 + 2];
    const float R = 0.03125f;  // rx=ry=rz = 1/32
    const float sh0 = ((s & 4) ? R : -R) + 1e-6f;
    const float sh1 = ((s & 2) ? R : -R) + 1e-6f;
    const float sh2 = ((s & 1) ? R : -R) + 1e-6f;
    const float LO = -1.0f + 1e-6f, HI = 1.0f - 1e-6f;
    float c0 = fminf(fmaxf(c0r + sh0, LO), HI);
    float c1 = fminf(fmaxf(c1r + sh1, LO), HI);
    float c2 = fminf(fmaxf(c2r + sh2, LO), HI);
    // channel0 -> z/D axis, channel1 -> y/H, channel2 -> x/W
    float z = (c0 + 1.0f) * 16.0f - 0.5f;
    float y = (c1 + 1.0f) * 16.0f - 0.5f;
    float x = (c2 + 1.0f) * 16.0f - 0.5f;
    float zf = floorf(z), yf = floorf(y), xf = floorf(x);
    float wz = z - zf, wy = y - yf, wx = x - xf;
    int z0 = min(max((int)zf, 0), 31), z1 = min(max((int)zf + 1, 0), 31);
    int y0 = min(max((int)yf, 0), 31), y1 = min(max((int)yf + 1, 0), 31);
    int x0 = min(max((int)xf, 0), 31), x1 = min(max((int)xf + 1, 0), 31);
    float wz0 = 1.0f - wz, wy0 = 1.0f - wy, wx0 = 1.0f - wx;

    float w[8] = { wz0 * wy0 * wx0, wz0 * wy0 * wx, wz0 * wy * wx0, wz0 * wy * wx,
                   wz  * wy0 * wx0, wz  * wy0 * wx, wz  * wy * wx0, wz  * wy * wx };
    int idx[8] = { (z0 * 32 + y0) * 32 + x0, (z0 * 32 + y0) * 32 + x1,
                   (z0 * 32 + y1) * 32 + x0, (z0 * 32 + y1) * 32 + x1,
                   (z1 * 32 + y0) * 32 + x0, (z1 * 32 + y0) * 32 + x1,
                   (z1 * 32 + y1) * 32 + x0, (z1 * 32 + y1) * 32 + x1 };

    float acc[16];
#pragma unroll
    for (int i = 0; i < 16; ++i) acc[i] = 0.0f;
#pragma unroll
    for (int corner = 0; corner < 8; ++corner) {
      const uint4* cp = (const uint4*)(feat + idx[corner] * 64 + p * 16);
      uint4 v0 = cp[0], v1 = cp[1];
      float wc = w[corner];
      unsigned vv[8] = { v0.x, v0.y, v0.z, v0.w, v1.x, v1.y, v1.z, v1.w };
#pragma unroll
      for (int d = 0; d < 8; ++d) {
        acc[2 * d]     += wc * bflo(vv[d]);
        acc[2 * d + 1] += wc * bfhi(vv[d]);
      }
    }
    unsigned pw[8];
#pragma unroll
    for (int d = 0; d < 8; ++d)
      pw[d] = cvt_pk_bf16(acc[2 * d], acc[2 * d + 1]);
    uint4* dst = (uint4*)(&sm_x[row * 104 + p * 16]);
    dst[0] = make_uint4(pw[0], pw[1], pw[2], pw[3]);
    dst[1] = make_uint4(pw[4], pw[5], pw[6], pw[7]);

    if (p == 0) {
      const float step = 2.0f / 31.0f;
      // q_coord channel mixing as in reference: ch0 from x-interp, ch2 from z-interp
      float qc0 = wx0 * (-1.0f + step * x0) + wx * (-1.0f + step * x1);
      float qc1 = wy0 * (-1.0f + step * y0) + wy * (-1.0f + step * y1);
      float qc2 = wz0 * (-1.0f + step * z0) + wz * (-1.0f + step * z1);
      float rel0 = (c0r - qc0) * 32.0f;
      float rel1 = (c1r - qc1) * 32.0f;
      float rel2 = (c2r - qc2) * 32.0f;
      sm_area[row] = fabsf(rel0 * rel1 * rel2) + 1e-9f;
      float cl0 = cell[q * 3 + 0], cl1 = cell[q * 3 + 1], cl2 = cell[q * 3 + 2];
      float ssq = fminf(fmaxf(8.0f / (fabsf(cl0 * cl1 * cl2) + 1e-8f), 1.0f), 64.0f);
      unsigned tw0 = cvt_pk_bf16(rel0, rel1);
      unsigned tw1 = cvt_pk_bf16(rel2, cl0 * 32.0f);
      unsigned tw2 = cvt_pk_bf16(cl1 * 32.0f, cl2 * 32.0f);
      unsigned tw3 = cvt_pk_bf16(ssq, 0.0f);  // element 71 zero-padded
      uint4* d2 = (uint4*)(&sm_x[row * 104 + 64]);
      d2[0] = make_uint4(tw0, tw1, tw2, tw3);
      d2[1] = make_uint4(0, 0, 0, 0);
      d2[2] = make_uint4(0, 0, 0, 0);
      d2[3] = make_uint4(0, 0, 0, 0);
    }
  }
  lgkm_barrier();  // sampling writes visible; nb prefetch stays in flight

  // ---------------- MLP layers (bf16 MFMA, fp32 accum) ----------------
  run_layer<3, true >(ws + W0F_OFF, b0, sm_x, 104, sm_h, ws + W1F_OFF, nb, wave, quad, l16, lane);
  run_layer<8, true >(ws + W1F_OFF, b1, sm_h, 264, sm_h, ws + W2F_OFF, nb, wave, quad, l16, lane);
  run_layer<8, false>(ws + W2F_OFF, b2, sm_h, 264, sm_h, nullptr,      nb, wave, quad, l16, lane);

  // ---------------- layer 3: 256 -> 1 (fp32 VALU, permuted W3 copy) ----------------
  {
    const int row = tid >> 2, p = tid & 3;
    const unsigned short* hp = sm_h + row * 264 + p * 64;
    const float* W3p = (const float*)(ws + W3P_OFF);
    float sum = 0.0f;
#pragma unroll
    for (int kk = 0; kk < 8; ++kk) {
      const uint4 v = *(const uint4*)(hp + kk * 8);
      const float4 wa = *(const float4*)(W3p + p * 64 + kk * 8);
      const float4 wb = *(const float4*)(W3p + p * 64 + kk * 8 + 4);
      sum += wa.x * bflo(v.x) + wa.y * bfhi(v.x);
      sum += wa.z * bflo(v.y) + wa.w * bfhi(v.y);
      sum += wb.x * bflo(v.z) + wb.y * bfhi(v.z);
      sum += wb.z * bflo(v.w) + wb.w * bfhi(v.w);
    }
    sum += __shfl_xor(sum, 1);
    sum += __shfl_xor(sum, 2);
    if (p == 0) sm_pred[row] = sum + b3[0];
  }
  lgkm_barrier();

  // ---------------- area-weighted combine (areas reversed) ----------------
  if (tid < 8) {
    const int ql = tid;
    float tot = 0.0f, ret = 0.0f;
#pragma unroll
    for (int s = 0; s < 8; ++s) tot += sm_area[ql * 8 + s];
#pragma unroll
    for (int s = 0; s < 8; ++s) ret += sm_pred[ql * 8 + s] * sm_area[ql * 8 + (7 - s)];
    out[blockIdx.x * 8 + ql] = ret / tot;
  }
}

extern "C" void kernel_launch(void* const* d_in, const int* in_sizes, int n_in,
                              void* d_out, int out_size, void* d_ws, size_t ws_size,
                              hipStream_t stream) {
  const float* inp   = (const float*)d_in[0];
  const float* coord = (const float*)d_in[1];
  const float* cell  = (const float*)d_in[2];
  const float* W0    = (const float*)d_in[3];
  const float* b0    = (const float*)d_in[4];
  const float* W1    = (const float*)d_in[5];
  const float* b1    = (const float*)d_in[6];
  const float* W2    = (const float*)d_in[7];
  const float* b2    = (const float*)d_in[8];
  const float* W3    = (const float*)d_in[9];
  const float* b3    = (const float*)d_in[10];
  unsigned short* ws = (unsigned short*)d_ws;
  float* out = (float*)d_out;

  const int Q = in_sizes[1] / 3;  // 131072
  // 512 feat tiles + 16 W1/W2 chunks + 96 W0 blocks + 1 W3 block = 625
  hipLaunchKernelGGL(liif_prep, dim3(625), dim3(256), 0, stream,
                     inp, W0, W1, W2, W3, ws);
  hipLaunchKernelGGL(liif_main, dim3(Q / 8), dim3(256), 0, stream,
                     coord, cell, b0, b1, b2, b3, ws, out);
}